// Round 17
// baseline (675.313 us; speedup 1.0000x reference)
//
#include <hip/hip_runtime.h>
#include <hip/hip_bf16.h>

#define NN 20000
#define NE 320000
#define NT 2048            // filter LUT entries over len in [0, 1.7321]

typedef _Float16 h2f __attribute__((ext_vector_type(2)));
typedef _Float16 f16x8 __attribute__((ext_vector_type(8)));
typedef float f32x4 __attribute__((ext_vector_type(4)));

__device__ __forceinline__ h2f u2h(unsigned int u){
  union { unsigned int u; h2f h; } v; v.u = u; return v.h;
}
__device__ __forceinline__ unsigned int h2u(h2f h){
  union { h2f h; unsigned int u; } v; v.h = h; return v.u;
}
__device__ __forceinline__ unsigned int pack2(float a, float b){
  h2f h; h.x = (_Float16)a; h.y = (_Float16)b;
  union { h2f h; unsigned int u; } v; v.h = h; return v.u;
}
__device__ __forceinline__ unsigned short f16b(float a){
  union { _Float16 h; unsigned short u; } v; v.h = (_Float16)a; return v.u;
}
__device__ __forceinline__ f16x8 u4h8(uint4 u){
  union { uint4 u; f16x8 h; } v; v.u = u; return v.h;
}
// packed f16 lerp: a + t*(b-a)
__device__ __forceinline__ unsigned int lerp2(unsigned int a, unsigned int b, h2f t){
  h2f ha = u2h(a), hb = u2h(b);
  return h2u(ha + t * (hb - ha));
}

// jax.nn.gelu default (approximate=True): 0.5x(1+tanh(t)) == x*sigmoid(2t)
__device__ __forceinline__ float geluf(float x){
  float t = 0.7978845608028654f * x * (1.0f + 0.044715f * x * x);
  return x / (1.0f + __expf(-2.0f * t));
}

// wave-local LDS fence: wave owns its smem; DS ops per wave execute in issue
// order, so only COMPILER reordering must be prevented.
__device__ __forceinline__ void wsync(){
  asm volatile("" ::: "memory");
  __builtin_amdgcn_sched_barrier(0);
}

struct TEnt { const float* src; float* dst; int R; int C; int trans; };
struct TTab { TEnt e[8]; };

__device__ __forceinline__ void lut_basis(int ent, float* b){
  float len = fmaxf((float)ent * (1.7321f / (float)(NT - 1)), 1e-6f);
  float sc = 3.1622776601683795f / fmaxf(len, 1e-6f);  // sqrt(2/MAXR)*sqrt(B)/r
#pragma unroll
  for (int k = 0; k < 10; k++)
    b[k] = sinf((float)(k + 1) * 1.5707963267948966f * len) * sc;
}

// ---------------- merged weight prep ----------------------------------------
// blocks: [0,6) convw, 6 = B-fragment pack, [7,7+2NT) layer LUT, rest init LUT
__global__ __launch_bounds__(384) void prep_k(
    TTab tb,
    const float* __restrict__ fABw1, const float* __restrict__ fABw2,
    const float* __restrict__ fCw1,  const float* __restrict__ fCw2,
    unsigned short* __restrict__ lutH,
    const float* __restrict__ f01w1, const float* __restrict__ f01w2,
    unsigned short* __restrict__ lut01H,
    const float* __restrict__ dlw1, const float* __restrict__ dlw2,
    unsigned int* __restrict__ bf1, unsigned int* __restrict__ bf2)
{
  int b = blockIdx.x;
  int t = threadIdx.x;
  if (b < 6){
    TEnt en = tb.e[b];
    int n = en.R * en.C;
    for (int i = t; i < n; i += 384){
      float v = en.src[i];
      if (en.trans){
        int r = i / en.C, c = i - r * en.C;
        en.dst[c * en.R + r] = v;
      } else {
        en.dst[i] = v;
      }
    }
    return;
  }
  if (b == 6){
    for (int i = t; i < 12288; i += 384){
      if (i < 6144){
        int v = i & 3, ln = (i >> 2) & 63;
        int nt = (i >> 8) & 1;
        int ktly = i >> 9;            // ly*6 + kt
        int kt = ktly % 6, ly = ktly / 6;
        int k = 32*kt + 8*(ln >> 4) + 2*v;
        int col = 16*nt + (ln & 15);
        const float* s = dlw1 + ly*6144;       // [192][32]
        bf1[i] = pack2(s[k*32 + col], s[(k+1)*32 + col]);
      } else {
        int j = i - 6144;
        int v = j & 3, ln = (j >> 2) & 63;
        int ntly = j >> 8;            // ly*12 + nt
        int nt = ntly % 12, ly = ntly / 12;
        int k = 8*(ln >> 4) + 2*v;
        int col = 16*nt + (ln & 15);
        const float* s = dlw2 + ly*6144;       // [32][192]
        bf2[j] = pack2(s[k*192 + col], s[(k+1)*192 + col]);
      }
    }
    return;
  }
  if (b < 7 + 2*NT){
    int bb = b - 7;
    int ent = bb & (NT - 1);
    int layer = bb >> 11;       // NT = 2048
    float bas[10];
    lut_basis(ent, bas);
    __shared__ float h[192];
    if (t < 192){
      int f = t >> 6, l = t & 63;       // f: 0=A, 1=B, 2=C
      const float* w1 = (f < 2) ? (fABw1 + (layer*2 + f) * 640)
                                : (fCw1 + layer * 640);
      float a = 0.f;
#pragma unroll
      for (int k = 0; k < 10; k++) a += bas[k] * w1[k*64 + l];
      h[t] = geluf(a);
    }
    __syncthreads();
    float a = 0.f;
    if (t < 192){
      int f = t / 96, j = t - 96 * f;
      const float* w2 = fABw2 + (layer*2 + f) * 6144;
      for (int l = 0; l < 64; l++) a += h[f*64 + l] * w2[l*96 + j];
    } else {
      int j = t - 192;
      const float* w2 = fCw2 + layer * 12288;
      for (int l = 0; l < 64; l++) a += h[128 + l] * w2[l*192 + j];
    }
    lutH[((long)(layer * NT + ent)) * 384 + t] = f16b(a);
    return;
  }
  // init LUT: 6 entries per block (384 = 6*64 threads)
  int blk = b - 7 - 2*NT;
  int ent = blk * 6 + (t >> 6);
  if (ent >= NT) return;
  int tl = t & 63;
  int p = tl >> 5, jj = tl & 31;
  float bas[10];
  lut_basis(ent, bas);
  const float* w1 = f01w1 + p * 640;
  const float* w2 = f01w2 + p * 2048;
  float W = 0.f;
  for (int l = 0; l < 64; l++){
    float a = 0.f;
#pragma unroll
    for (int k = 0; k < 10; k++) a += bas[k] * w1[k*64 + l];
    W += geluf(a) * w2[l*32 + jj];
  }
  lut01H[(long)ent * 64 + tl] = f16b(W);
}

// ---------------- merged: edge degree count + node init ---------------------
__global__ __launch_bounds__(256) void countnode_k(
    const int* __restrict__ esrc, const int* __restrict__ edst,
    int* __restrict__ cntd, int* __restrict__ cnts,
    const int* __restrict__ az, const float* __restrict__ embedF,
    const float* __restrict__ w1T /*[32][8]*/, const float* __restrict__ w2T /*[32][32]*/,
    float* __restrict__ xn)
{
  if (blockIdx.x < NE/256){
    int e = blockIdx.x * 256 + threadIdx.x;
    atomicAdd(cntd + edst[e], 1);
    atomicAdd(cnts + esrc[e], 1);
    return;
  }
  int n = (blockIdx.x - NE/256) * 256 + threadIdx.x;
  if (n >= NN) return;
  int z = az[n];
  float ee[8];
#pragma unroll
  for (int k = 0; k < 8; k++) ee[k] = embedF[z * 8 + k];
  float hid[32];
#pragma unroll
  for (int l = 0; l < 32; l++){
    float a = 0.f;
#pragma unroll
    for (int k = 0; k < 8; k++) a += ee[k] * w1T[l * 8 + k];
    hid[l] = geluf(a);
  }
  float* row = xn + (long)n * 96;
#pragma unroll
  for (int j = 0; j < 32; j++){
    float a = 0.f;
#pragma unroll
    for (int l = 0; l < 32; l++) a += hid[l] * w2T[j * 32 + l];
    row[j] = a;
  }
#pragma unroll
  for (int j = 32; j < 96; j++) row[j] = 0.f;
}

// ---------------- both prefix sums in one launch ----------------------------
__global__ __launch_bounds__(1024) void prefix_k(
    const int* __restrict__ cntd, int* __restrict__ doff, int* __restrict__ curd,
    const int* __restrict__ cnts, int* __restrict__ soff, int* __restrict__ curs)
{
  const int* cnt = blockIdx.x ? cnts : cntd;
  int* off = blockIdx.x ? soff : doff;
  int* cur = blockIdx.x ? curs : curd;
  __shared__ int part[1024];
  int t = threadIdx.x;
  int base = t * 20;
  int s = 0;
  for (int i = 0; i < 20; i++){ int idx = base + i; if (idx < NN) s += cnt[idx]; }
  part[t] = s; __syncthreads();
  for (int d = 1; d < 1024; d <<= 1){
    int v = (t >= d) ? part[t - d] : 0;
    __syncthreads();
    part[t] += v;
    __syncthreads();
  }
  int run = (t == 0) ? 0 : part[t - 1];
  for (int i = 0; i < 20; i++){
    int idx = base + i;
    if (idx < NN){ off[idx] = run; cur[idx] = run; run += cnt[idx]; }
  }
  if (t == 0) off[NN] = NE;
}

// p = dst-sorted slot of edge e; q = src-sorted slot; qpos[p]=q
__global__ void fill_comb(const int* __restrict__ esrc, const int* __restrict__ edst,
                          int* __restrict__ curd, int* __restrict__ curs,
                          int* __restrict__ srcS, int* __restrict__ dstS,
                          int* __restrict__ qpos){
  int e = blockIdx.x * 256 + threadIdx.x;
  if (e >= NE) return;
  int s = esrc[e], d = edst[e];
  int p = atomicAdd(curd + d, 1);
  srcS[p] = s; dstS[p] = d;
  int q = atomicAdd(curs + s, 1);
  qpos[p] = q;
}

// ---------------- edge init: p-row (dst side) + scattered q-row (src side) --
__global__ __launch_bounds__(256) void edge_init(
    const float* __restrict__ pos, const int* __restrict__ srcS,
    const int* __restrict__ dstS, const int* __restrict__ qpos,
    float* __restrict__ els,
    unsigned short* __restrict__ pbuf0, unsigned short* __restrict__ qbuf0,
    const float* __restrict__ w1T /*dl1w1T [32][4]*/, const float* __restrict__ w2T /*[32][32]*/,
    const unsigned int* __restrict__ lut01)
{
  int p = blockIdx.x * 256 + threadIdx.x;
  if (p >= NE) return;
  int s = srcS[p], d = dstS[p];
  float x = pos[s*3+0] - pos[d*3+0];
  float y = pos[s*3+1] - pos[d*3+1];
  float z = pos[s*3+2] - pos[d*3+2];
  float L = sqrtf(x*x + y*y + z*z + 1e-12f);
  float iv = 1.0f / fmaxf(L, 1e-6f);
  els[p] = L;

  float u = L - 2.0f;   // 2*(len/MAXR - 1), MAXR=2
  float cut = 0.5f * (1.0f - cosf(3.14159265358979323f * u));
  cut = (u > 0.0f) ? 0.0f : cut;
  cut = (u < -1.0f) ? 1.0f : cut;
  float xe0 = cut, cc = cut * 1.7320508075688772f * iv;
  float xe1 = cc*x, xe2 = cc*y, xe3 = cc*z;
  float hid[32];
#pragma unroll
  for (int l = 0; l < 32; l++){
    float a = xe0*w1T[l*4+0] + xe1*w1T[l*4+1] + xe2*w1T[l*4+2] + xe3*w1T[l*4+3];
    hid[l] = geluf(a);
  }
  float xeh[32];
#pragma unroll
  for (int j = 0; j < 32; j++){
    float a = 0.f;
#pragma unroll
    for (int l = 0; l < 32; l++) a += hid[l] * w2T[j*32 + l];
    xeh[j] = a;
  }
  float tt = fminf(L * ((float)(NT-1) / 1.7321f), (float)(NT-1) - 0.001f);
  int i0 = (int)tt; float tfv = tt - (float)i0;
  h2f tf2; tf2.x = (_Float16)tfv; tf2.y = tf2.x;
  h2f h05; h05.x = (_Float16)0.5f; h05.y = h05.x;
  const unsigned int* rA = lut01 + i0 * 32;
  const unsigned int* rB = rA + 32;

  unsigned int xp[16];
#pragma unroll
  for (int jp = 0; jp < 16; jp++)
    xp[jp] = pack2(xeh[2*jp] * 0.0625f, xeh[2*jp+1] * 0.0625f);

  unsigned int du[16], au[16];
#pragma unroll
  for (int q = 0; q < 4; q++){
    uint4 a = ((const uint4*)rA)[q];
    uint4 b = ((const uint4*)rB)[q];
    du[4*q+0] = h2u(u2h(lerp2(a.x, b.x, tf2)) * u2h(xp[4*q+0]));
    du[4*q+1] = h2u(u2h(lerp2(a.y, b.y, tf2)) * u2h(xp[4*q+1]));
    du[4*q+2] = h2u(u2h(lerp2(a.z, b.z, tf2)) * u2h(xp[4*q+2]));
    du[4*q+3] = h2u(u2h(lerp2(a.w, b.w, tf2)) * u2h(xp[4*q+3]));
  }
#pragma unroll
  for (int q = 0; q < 4; q++){
    uint4 a = ((const uint4*)(rA + 16))[q];
    uint4 b = ((const uint4*)(rB + 16))[q];
    au[4*q+0] = h2u(u2h(lerp2(a.x, b.x, tf2)) * u2h(xp[4*q+0]) * h05);
    au[4*q+1] = h2u(u2h(lerp2(a.y, b.y, tf2)) * u2h(xp[4*q+1]) * h05);
    au[4*q+2] = h2u(u2h(lerp2(a.z, b.z, tf2)) * u2h(xp[4*q+2]) * h05);
    au[4*q+3] = h2u(u2h(lerp2(a.w, b.w, tf2)) * u2h(xp[4*q+3]) * h05);
  }
  unsigned short* prow = pbuf0 + (long)p * 64;
  unsigned short* qrow = qbuf0 + (long)qpos[p] * 64;
#pragma unroll
  for (int q = 0; q < 4; q++){
    ((uint4*)prow)[q]      = ((uint4*)du)[q];
    ((uint4*)(prow+32))[q] = ((uint4*)au)[q];
  }
  unsigned int nd[16];
#pragma unroll
  for (int i = 0; i < 16; i++) nd[i] = du[i] ^ 0x80008000u;  // negate packed f16
#pragma unroll
  for (int q = 0; q < 4; q++){
    ((uint4*)qrow)[q]      = ((uint4*)nd)[q];
    ((uint4*)(qrow+32))[q] = ((uint4*)au)[q];
  }
}

// 16 nodes per 256-thread block, 16 threads/node, uint2-vectorized streams
__global__ __launch_bounds__(256) void gather_init(
    const int* __restrict__ doff, const int* __restrict__ soff,
    const unsigned short* __restrict__ pbuf0, const unsigned short* __restrict__ qbuf0,
    float* __restrict__ xn, unsigned int* __restrict__ xnh)
{
  int g = threadIdx.x >> 4;          // 0..15
  int c4 = threadIdx.x & 15;         // 4-half group within 64-half row
  int n = blockIdx.x * 16 + g;
  if (n >= NN) return;
  const uint2* p2 = (const uint2*)pbuf0;   // row = 16 uint2
  const uint2* q2 = (const uint2*)qbuf0;
  float a0 = 0.f, a1 = 0.f, a2 = 0.f, a3 = 0.f;
  int d1 = doff[n+1];
  for (int p = doff[n]; p < d1; p++){
    uint2 v = p2[(long)p * 16 + c4];
    h2f lo = u2h(v.x), hi = u2h(v.y);
    a0 += (float)lo.x; a1 += (float)lo.y; a2 += (float)hi.x; a3 += (float)hi.y;
  }
  int s1 = soff[n+1];
  for (int q = soff[n]; q < s1; q++){
    uint2 v = q2[(long)q * 16 + c4];
    h2f lo = u2h(v.x), hi = u2h(v.y);
    a0 += (float)lo.x; a1 += (float)lo.y; a2 += (float)hi.x; a3 += (float)hi.y;
  }
  float4 v4; v4.x = 16.f*a0; v4.y = 16.f*a1; v4.z = 16.f*a2; v4.w = 16.f*a3;
  *(float4*)(xn + (long)n * 96 + 32 + 4*c4) = v4;   // cols 32..95
  uint2 w; w.x = pack2(v4.x, v4.y); w.y = pack2(v4.z, v4.w);
  *(uint2*)(xnh + n * 48 + 16 + 2*c4) = w;
  if (c4 < 8){
    float4 t = *(const float4*)(xn + (long)n * 96 + 4*c4);
    uint2 w0; w0.x = pack2(t.x, t.y); w0.y = pack2(t.z, t.w);
    *(uint2*)(xnh + n * 48 + 2*c4) = w0;
  }
}

// ---------------- conv layer via MFMA: 1 wave/block, batched loads ----------
// r17: q-row staged in registers (qst[48], statically indexed) and written as
// one contiguous 192B burst at the end -> kills scattered-write inflation
// (r16 WRITE_SIZE 214MB vs 123MB payload).
// Per wave: 64 edges. pass1 hd[64][32] = G[64][192] @ dw1; pass2 d = hdg @ dw2.
// A-frag: lane -> row (lane&15)+16mt, k = 8*(lane>>4)+j
// B-frag: lane -> col (lane&15)+16nt, k = 8*(lane>>4)+j (pre-packed bf1/bf2)
// C/D:    lane -> col (lane&15), row = 4*(lane>>4)+reg
// p-row -> pbuf[p]; q-row -> qbuf[qpos[p]] (scatter; gather streams both sides)
__global__ __launch_bounds__(64) void layer_k(
    const int* __restrict__ srcS, const int* __restrict__ dstS,
    const int* __restrict__ qpos,
    const float* __restrict__ els, const unsigned int* __restrict__ xnh,
    unsigned short* __restrict__ pbuf, unsigned short* __restrict__ qbuf,
    const unsigned int* __restrict__ lut,
    const unsigned int* __restrict__ bf1, const unsigned int* __restrict__ bf2)
{
  __shared__ unsigned int wb[1092];   // [64][17]-uint image, one wave
  int lane = threadIdx.x;
  int g = lane >> 4, r15 = lane & 15;
  int wbase = blockIdx.x * 64;

  // per-mt metadata (fragment-side edges: re = wbase + 16mt + r15)
  const unsigned int* xsP[4]; const unsigned int* xdP[4];
  const unsigned int* rAm[4]; const unsigned int* rBm[4];
  h2f tfm[4];
#pragma unroll
  for (int mt = 0; mt < 4; mt++){
    int re = wbase + 16*mt + r15;
    xsP[mt] = xnh + srcS[re] * 48;
    xdP[mt] = xnh + dstS[re] * 48;
    float L = els[re];
    float tt = fminf(L * ((float)(NT-1) / 1.7321f), (float)(NT-1) - 0.001f);
    int i0 = (int)tt; float tfv = tt - (float)i0;
    h2f tf; tf.x = (_Float16)tfv; tf.y = tf.x;
    tfm[mt] = tf;
    rAm[mt] = lut + (long)i0 * 192;
    rBm[mt] = rAm[mt] + 192;
  }
  // own-edge metadata (output row p = wbase + lane)
  int p = wbase + lane;
  int qq = qpos[p];
  const unsigned int *rAo, *rBo; h2f tfo;
  {
    float L = els[p];
    float tt = fminf(L * ((float)(NT-1) / 1.7321f), (float)(NT-1) - 0.001f);
    int i0 = (int)tt; float tfv = tt - (float)i0;
    tfo.x = (_Float16)tfv; tfo.y = tfo.x;
    rAo = lut + (long)i0 * 192;
    rBo = rAo + 192;
  }
  h2f c32; c32.x = (_Float16)0.03125f;  c32.y = c32.x;
  h2f c64; c64.x = (_Float16)0.015625f; c64.y = c64.x;
  h2f h05; h05.x = (_Float16)0.5f;      h05.y = h05.x;
  f32x4 zf = {0.f, 0.f, 0.f, 0.f};

  // ---- pass 1 (batched loads per ktp window) ----
  f32x4 acc[4][2];
#pragma unroll
  for (int mt = 0; mt < 4; mt++){ acc[mt][0] = zf; acc[mt][1] = zf; }

#pragma unroll
  for (int ktp = 0; ktp < 3; ktp++){      // x-uint window 16*ktp..+16
    int off = 16*ktp + 4*g;
    uint4 bg0 = *(const uint4*)(bf1 + (((ktp  )*2 + 0)*64 + lane)*4);
    uint4 bg1 = *(const uint4*)(bf1 + (((ktp  )*2 + 1)*64 + lane)*4);
    uint4 ba0 = *(const uint4*)(bf1 + (((ktp+3)*2 + 0)*64 + lane)*4);
    uint4 ba1 = *(const uint4*)(bf1 + (((ktp+3)*2 + 1)*64 + lane)*4);
    uint4 xs4[4], xd4[4], waA[4], waB[4], wbA[4], wbB[4];
#pragma unroll
    for (int mt = 0; mt < 4; mt++){
      xs4[mt] = *(const uint4*)(xsP[mt] + off);
      xd4[mt] = *(const uint4*)(xdP[mt] + off);
      waA[mt] = *(const uint4*)(rAm[mt] + off);
      waB[mt] = *(const uint4*)(rBm[mt] + off);
      wbA[mt] = *(const uint4*)(rAm[mt] + 48 + off);
      wbB[mt] = *(const uint4*)(rBm[mt] + 48 + off);
    }
#pragma unroll
    for (int mt = 0; mt < 4; mt++){
      h2f tf = tfm[mt];
      uint4 fg, fa;
      fg.x = h2u(u2h(lerp2(waA[mt].x, waB[mt].x, tf)) * ((u2h(xd4[mt].x) - u2h(xs4[mt].x)) * c32));
      fg.y = h2u(u2h(lerp2(waA[mt].y, waB[mt].y, tf)) * ((u2h(xd4[mt].y) - u2h(xs4[mt].y)) * c32));
      fg.z = h2u(u2h(lerp2(waA[mt].z, waB[mt].z, tf)) * ((u2h(xd4[mt].z) - u2h(xs4[mt].z)) * c32));
      fg.w = h2u(u2h(lerp2(waA[mt].w, waB[mt].w, tf)) * ((u2h(xd4[mt].w) - u2h(xs4[mt].w)) * c32));
      fa.x = h2u(u2h(lerp2(wbA[mt].x, wbB[mt].x, tf)) * ((u2h(xd4[mt].x) + u2h(xs4[mt].x)) * c64));
      fa.y = h2u(u2h(lerp2(wbA[mt].y, wbB[mt].y, tf)) * ((u2h(xd4[mt].y) + u2h(xs4[mt].y)) * c64));
      fa.z = h2u(u2h(lerp2(wbA[mt].z, wbB[mt].z, tf)) * ((u2h(xd4[mt].z) + u2h(xs4[mt].z)) * c64));
      fa.w = h2u(u2h(lerp2(wbA[mt].w, wbB[mt].w, tf)) * ((u2h(xd4[mt].w) + u2h(xs4[mt].w)) * c64));
      acc[mt][0] = __builtin_amdgcn_mfma_f32_16x16x32_f16(u4h8(fg), u4h8(bg0), acc[mt][0], 0, 0, 0);
      acc[mt][1] = __builtin_amdgcn_mfma_f32_16x16x32_f16(u4h8(fg), u4h8(bg1), acc[mt][1], 0, 0, 0);
      acc[mt][0] = __builtin_amdgcn_mfma_f32_16x16x32_f16(u4h8(fa), u4h8(ba0), acc[mt][0], 0, 0, 0);
      acc[mt][1] = __builtin_amdgcn_mfma_f32_16x16x32_f16(u4h8(fa), u4h8(ba1), acc[mt][1], 0, 0, 0);
    }
  }

  // ---- gelu + transpose hdg (D layout -> row-major LDS -> A-frags) ----
#pragma unroll
  for (int mt = 0; mt < 4; mt++)
#pragma unroll
    for (int nt = 0; nt < 2; nt++)
#pragma unroll
      for (int i = 0; i < 4; i++){
        float v = geluf(32.f * acc[mt][nt][i]) * 0.015625f;
        float o = __shfl_xor(v, 1);
        if (!(lane & 1))
          wb[(16*mt + 4*g + i)*17 + 8*nt + (r15 >> 1)] = pack2(v, o);
      }
  wsync();
  uint4 af[4];
#pragma unroll
  for (int mt = 0; mt < 4; mt++){
    int row = 16*mt + r15;
    af[mt].x = wb[row*17 + 4*g + 0];
    af[mt].y = wb[row*17 + 4*g + 1];
    af[mt].z = wb[row*17 + 4*g + 2];
    af[mt].w = wb[row*17 + 4*g + 3];
  }
  wsync();

  // ---- pass 2: per 16-col block np; q-row staged in registers -------------
  unsigned int* prow = (unsigned int*)(pbuf + (long)p * 96);
  unsigned int* qrow = (unsigned int*)(qbuf + (long)qq * 96);
  unsigned int qst[48];
#pragma unroll
  for (int np = 0; np < 6; np++){
    uint4 b1 = *(const uint4*)(bf2 + ((np    )*64 + lane)*4);
    uint4 b2 = *(const uint4*)(bf2 + ((np + 6)*64 + lane)*4);
    // own-edge Wc loads issued early (overlap with MFMA below)
    uint4 ca0 = *(const uint4*)(rAo + 96  + 8*np);
    uint4 ca1 = *(const uint4*)(rAo + 100 + 8*np);
    uint4 cb0 = *(const uint4*)(rBo + 96  + 8*np);
    uint4 cb1 = *(const uint4*)(rBo + 100 + 8*np);
    uint4 ka0 = *(const uint4*)(rAo + 144 + 8*np);
    uint4 ka1 = *(const uint4*)(rAo + 148 + 8*np);
    uint4 kb0 = *(const uint4*)(rBo + 144 + 8*np);
    uint4 kb1 = *(const uint4*)(rBo + 148 + 8*np);
    f32x4 d1a[4], d2a[4];
#pragma unroll
    for (int mt = 0; mt < 4; mt++){
      d1a[mt] = __builtin_amdgcn_mfma_f32_16x16x32_f16(u4h8(af[mt]), u4h8(b1), zf, 0, 0, 0);
      d2a[mt] = __builtin_amdgcn_mfma_f32_16x16x32_f16(u4h8(af[mt]), u4h8(b2), zf, 0, 0, 0);
    }
#pragma unroll
    for (int mt = 0; mt < 4; mt++)
#pragma unroll
      for (int i = 0; i < 4; i++){
        float v1 = d1a[mt][i], v2 = d2a[mt][i];
        float o1 = __shfl_xor(v1, 1);
        float o2 = __shfl_xor(v2, 1);
        if (!(lane & 1)){
          int r = 16*mt + 4*g + i;
          wb[r*17 + (r15 >> 1)]     = pack2(v1, o1);
          wb[r*17 + 8 + (r15 >> 1)] = pack2(v2, o2);
        }
      }
    wsync();
    unsigned int d1u[8], d2u[8];
#pragma unroll
    for (int u = 0; u < 8; u++){
      d1u[u] = wb[lane*17 + u];
      d2u[u] = wb[lane*17 + 8 + u];
    }
    wsync();
    unsigned int c1u[8] = {lerp2(ca0.x,cb0.x,tfo), lerp2(ca0.y,cb0.y,tfo),
                           lerp2(ca0.z,cb0.z,tfo), lerp2(ca0.w,cb0.w,tfo),
                           lerp2(ca1.x,cb1.x,tfo), lerp2(ca1.y,cb1.y,tfo),
                           lerp2(ca1.z,cb1.z,tfo), lerp2(ca1.w,cb1.w,tfo)};
    unsigned int c2u[8] = {lerp2(ka0.x,kb0.x,tfo), lerp2(ka0.y,kb0.y,tfo),
                           lerp2(ka0.z,kb0.z,tfo), lerp2(ka0.w,kb0.w,tfo),
                           lerp2(ka1.x,kb1.x,tfo), lerp2(ka1.y,kb1.y,tfo),
                           lerp2(ka1.z,kb1.z,tfo), lerp2(ka1.w,kb1.w,tfo)};
    unsigned int pv[8];
#pragma unroll
    for (int u = 0; u < 8; u++){
      h2f t1 = u2h(c1u[u]) * u2h(d1u[u]);            // dv (true/64)
      h2f t2 = (u2h(c2u[u]) * u2h(d2u[u])) * h05;    // av (true/64)
      pv[u] = h2u(t1 + t2);
      qst[np*8 + u] = h2u(t2 - t1);
    }
    *(uint4*)(prow + 8*np)     = *(uint4*)(pv);
    *(uint4*)(prow + 8*np + 4) = *(uint4*)(pv + 4);
  }
  // single contiguous 192B q-row burst (avoids partial-sector writebacks)
#pragma unroll
  for (int i = 0; i < 12; i++)
    *(uint4*)(qrow + 4*i) = ((uint4*)qst)[i];
}

// fused gather + node update + xnh repack; uint2-vectorized, 10 nodes/block
__global__ __launch_bounds__(256) void gather_upd(
    const int* __restrict__ doff, const int* __restrict__ soff,
    const unsigned short* __restrict__ pbuf, const unsigned short* __restrict__ qbuf,
    float* __restrict__ xn, unsigned int* __restrict__ xnh)
{
  int g = threadIdx.x / 24;
  int c4 = threadIdx.x - 24 * g;     // 4-half group within 96-half row
  if (g >= 10) return;
  int n = blockIdx.x * 10 + g;
  if (n >= NN) return;
  const uint2* p2 = (const uint2*)pbuf;   // row = 24 uint2
  const uint2* q2 = (const uint2*)qbuf;
  float a0 = 0.f, a1 = 0.f, a2 = 0.f, a3 = 0.f;
  int d1 = doff[n+1];
  for (int p = doff[n]; p < d1; p++){
    uint2 v = p2[(long)p * 24 + c4];
    h2f lo = u2h(v.x), hi = u2h(v.y);
    a0 += (float)lo.x; a1 += (float)lo.y; a2 += (float)hi.x; a3 += (float)hi.y;
  }
  int s1 = soff[n+1];
  for (int q = soff[n]; q < s1; q++){
    uint2 v = q2[(long)q * 24 + c4];
    h2f lo = u2h(v.x), hi = u2h(v.y);
    a0 += (float)lo.x; a1 += (float)lo.y; a2 += (float)hi.x; a3 += (float)hi.y;
  }
  float4 xo = *(float4*)(xn + (long)n * 96 + 4*c4);
  xo.x -= 6.4f * a0; xo.y -= 6.4f * a1; xo.z -= 6.4f * a2; xo.w -= 6.4f * a3;
  *(float4*)(xn + (long)n * 96 + 4*c4) = xo;
  uint2 w; w.x = pack2(xo.x, xo.y); w.y = pack2(xo.z, xo.w);
  *(uint2*)(xnh + n * 48 + 2*c4) = w;
}

// ---------------- column sum over nodes -------------------------------------
__global__ void colsum(const float* __restrict__ xn, float* __restrict__ nodesum){
  int col = threadIdx.x % 96;
  int seg = threadIdx.x / 96;
  int stripe = blockIdx.x * 2 + seg;   // 0..399
  float acc = 0.f;
  for (int n = stripe; n < NN; n += 400) acc += xn[(long)n * 96 + col];
  unsafeAtomicAdd(nodesum + col, acc);
}

// ---------------- project to 16 outputs, scale, fp32 store ------------------
__global__ void project(const float* __restrict__ nodesum, const float* __restrict__ siT,
                        float* __restrict__ out){
  int j = threadIdx.x;
  if (j < 16){
    float a = 0.f;
#pragma unroll
    for (int c = 0; c < 96; c++) a += nodesum[c] * siT[j*96 + c];
    out[j] = a * 0.007071067811865475f;   // 1/sqrt(20000)
  }
}

// ---------------- host side -------------------------------------------------
extern "C" void kernel_launch(void* const* d_in, const int* in_sizes, int n_in,
                              void* d_out, int out_size, void* d_ws, size_t ws_size,
                              hipStream_t stream){
  const float* pos  = (const float*)d_in[0];
  const int* atom_z = (const int*)d_in[1];
  const int* esrc   = (const int*)d_in[2];
  const int* edst   = (const int*)d_in[3];

  float* ws      = (float*)d_ws;
  float* xn      = ws;                  // 1,920,000
  float* nodesum = ws + 1920000;        // 96
  float* WB      = ws + 1920096;        // 4,128 fp32 weights
  unsigned int* bf1   = (unsigned int*)(ws + 1924224);  // 6,144
  unsigned int* bf2   = (unsigned int*)(ws + 1930368);  // 6,144
  unsigned int* lutL  = (unsigned int*)(ws + 1936512);  // 786,432 (3 MB)
  unsigned int* lut01 = (unsigned int*)(ws + 2722944);  // 65,536
  unsigned int* xnh   = (unsigned int*)(ws + 2788480);  // 960,000 (f16 rows)
  float* els    = ws + 3748480;                 // 320,000 edge lengths
  int*   cntd   = (int*)(ws + 4068480);         // 20,000
  int*   cnts   = cntd + 20000;                 // 20,000 (contiguous for 1 memset)
  int*   curd   = cnts + 20000;                 // 20,000
  int*   curs   = curd + 20000;                 // 20,000
  int*   doff   = curs + 20000;                 // 20,004
  int*   soff   = doff + 20004;                 // 20,004  -> ends 4,188,488
  int*   srcS   = soff + 20004;                 // 320,000 -> ends 4,508,488
  int*   dstS   = srcS + 320000;                // 320,000 -> ends 4,828,488
  int*   qpos   = dstS + 320000;                // 320,000 -> ends 5,148,488
  // buffers at verified round-10..16 offsets (>= 5,468,496 > int arrays):
  //   pbufL: [ 5,468,496 .. 20,828,496)   qbufL: [20,828,496 .. 36,188,496)
  //   pbuf0: [ 5,468,496 .. 15,708,496)   qbuf0: [15,708,496 .. 25,948,496)
  // (init aliases layer space CROSS-PHASE only; init-phase disjoint.)
  // end = 36,188,496 floats = 144.8 MB
  unsigned short* pbufL = (unsigned short*)(ws + 5468496);
  unsigned short* qbufL = (unsigned short*)(ws + 20828496);
  unsigned short* pbuf0 = (unsigned short*)(ws + 5468496);
  unsigned short* qbuf0 = (unsigned short*)(ws + 15708496);

  float* embedF = WB + 0;        // 160
  float* dl0w1T = WB + 160;      // 256   [32][8]
  float* dl0w2T = WB + 416;      // 1024  [32][32]
  float* dl1w1T = WB + 1440;     // 128   [32][4]
  float* dl1w2T = WB + 1568;     // 1024  [32][32]
  float* siT    = WB + 2592;     // 1536  [16][96]

  hipMemsetAsync(cntd, 0, 40000 * 4, stream);
  hipMemsetAsync(nodesum, 0, 96 * 4, stream);

  TTab tb;
  int ti = 0;
  auto add = [&](const void* s, float* dst, int R, int C, int tr){
    tb.e[ti].src = (const float*)s; tb.e[ti].dst = dst;
    tb.e[ti].R = R; tb.e[ti].C = C; tb.e[ti].trans = tr; ti++;
  };
  add(d_in[4],  embedF, 20, 8, 0);
  add(d_in[5],  dl0w1T, 8, 32, 1);
  add(d_in[6],  dl0w2T, 32, 32, 1);
  add(d_in[7],  dl1w1T, 4, 32, 1);
  add(d_in[8],  dl1w2T, 32, 32, 1);
  add(d_in[17], siT, 96, 16, 1);

  // weight prep (convw + MFMA B-fragment pack + both LUTs) in one launch
  prep_k<<<7 + 2*NT + (NT + 5)/6, 384, 0, stream>>>(
      tb, (const float*)d_in[11], (const float*)d_in[12],
      (const float*)d_in[13], (const float*)d_in[14], (unsigned short*)lutL,
      (const float*)d_in[9], (const float*)d_in[10], (unsigned short*)lut01,
      (const float*)d_in[15], (const float*)d_in[16], bf1, bf2);
  countnode_k<<<NE/256 + (NN + 255)/256, 256, 0, stream>>>(
      esrc, edst, cntd, cnts, atom_z, embedF, dl0w1T, dl0w2T, xn);
  prefix_k<<<2, 1024, 0, stream>>>(cntd, doff, curd, cnts, soff, curs);
  fill_comb<<<(NE + 255)/256, 256, 0, stream>>>(esrc, edst, curd, curs,
                                                srcS, dstS, qpos);
  edge_init<<<(NE + 255)/256, 256, 0, stream>>>(
      pos, srcS, dstS, qpos, els, pbuf0, qbuf0, dl1w1T, dl1w2T, lut01);
  gather_init<<<(NN + 15)/16, 256, 0, stream>>>(doff, soff, pbuf0, qbuf0, xn, xnh);

  for (int i = 0; i < 2; i++){
    layer_k<<<NE/64, 64, 0, stream>>>(
        srcS, dstS, qpos, els, xnh, pbufL, qbufL,
        lutL + (long)i * NT * 192, bf1 + i*3072, bf2 + i*3072);
    gather_upd<<<(NN + 9)/10, 256, 0, stream>>>(doff, soff, pbufL, qbufL,
                                                xn, xnh);
  }
  colsum<<<200, 192, 0, stream>>>(xn, nodesum);
  project<<<1, 64, 0, stream>>>(nodesum, siT, (float*)d_out);
}

// Round 18
// 638.834 us; speedup vs baseline: 1.0571x; 1.0571x over previous
//
#include <hip/hip_runtime.h>
#include <hip/hip_bf16.h>

#define NN 20000
#define NE 320000
#define NT 2048            // filter LUT entries over len in [0, 1.7321]

typedef _Float16 h2f __attribute__((ext_vector_type(2)));
typedef _Float16 f16x8 __attribute__((ext_vector_type(8)));
typedef float f32x4 __attribute__((ext_vector_type(4)));

__device__ __forceinline__ h2f u2h(unsigned int u){
  union { unsigned int u; h2f h; } v; v.u = u; return v.h;
}
__device__ __forceinline__ unsigned int h2u(h2f h){
  union { h2f h; unsigned int u; } v; v.h = h; return v.u;
}
__device__ __forceinline__ unsigned int pack2(float a, float b){
  h2f h; h.x = (_Float16)a; h.y = (_Float16)b;
  union { h2f h; unsigned int u; } v; v.h = h; return v.u;
}
__device__ __forceinline__ unsigned short f16b(float a){
  union { _Float16 h; unsigned short u; } v; v.h = (_Float16)a; return v.u;
}
__device__ __forceinline__ f16x8 u4h8(uint4 u){
  union { uint4 u; f16x8 h; } v; v.u = u; return v.h;
}
// packed f16 lerp: a + t*(b-a)
__device__ __forceinline__ unsigned int lerp2(unsigned int a, unsigned int b, h2f t){
  h2f ha = u2h(a), hb = u2h(b);
  return h2u(ha + t * (hb - ha));
}

// jax.nn.gelu default (approximate=True): 0.5x(1+tanh(t)) == x*sigmoid(2t)
__device__ __forceinline__ float geluf(float x){
  float t = 0.7978845608028654f * x * (1.0f + 0.044715f * x * x);
  return x / (1.0f + __expf(-2.0f * t));
}

// wave-local LDS fence: wave owns its smem; DS ops per wave execute in issue
// order, so only COMPILER reordering must be prevented.
__device__ __forceinline__ void wsync(){
  asm volatile("" ::: "memory");
  __builtin_amdgcn_sched_barrier(0);
}

struct TEnt { const float* src; float* dst; int R; int C; int trans; };
struct TTab { TEnt e[8]; };

__device__ __forceinline__ void lut_basis(int ent, float* b){
  float len = fmaxf((float)ent * (1.7321f / (float)(NT - 1)), 1e-6f);
  float sc = 3.1622776601683795f / fmaxf(len, 1e-6f);  // sqrt(2/MAXR)*sqrt(B)/r
#pragma unroll
  for (int k = 0; k < 10; k++)
    b[k] = sinf((float)(k + 1) * 1.5707963267948966f * len) * sc;
}

// ---------------- merged weight prep ----------------------------------------
// blocks: [0,6) convw, 6 = B-fragment pack, [7,7+2NT) layer LUT, rest init LUT
__global__ __launch_bounds__(384) void prep_k(
    TTab tb,
    const float* __restrict__ fABw1, const float* __restrict__ fABw2,
    const float* __restrict__ fCw1,  const float* __restrict__ fCw2,
    unsigned short* __restrict__ lutH,
    const float* __restrict__ f01w1, const float* __restrict__ f01w2,
    unsigned short* __restrict__ lut01H,
    const float* __restrict__ dlw1, const float* __restrict__ dlw2,
    unsigned int* __restrict__ bf1, unsigned int* __restrict__ bf2)
{
  int b = blockIdx.x;
  int t = threadIdx.x;
  if (b < 6){
    TEnt en = tb.e[b];
    int n = en.R * en.C;
    for (int i = t; i < n; i += 384){
      float v = en.src[i];
      if (en.trans){
        int r = i / en.C, c = i - r * en.C;
        en.dst[c * en.R + r] = v;
      } else {
        en.dst[i] = v;
      }
    }
    return;
  }
  if (b == 6){
    for (int i = t; i < 12288; i += 384){
      if (i < 6144){
        int v = i & 3, ln = (i >> 2) & 63;
        int nt = (i >> 8) & 1;
        int ktly = i >> 9;            // ly*6 + kt
        int kt = ktly % 6, ly = ktly / 6;
        int k = 32*kt + 8*(ln >> 4) + 2*v;
        int col = 16*nt + (ln & 15);
        const float* s = dlw1 + ly*6144;       // [192][32]
        bf1[i] = pack2(s[k*32 + col], s[(k+1)*32 + col]);
      } else {
        int j = i - 6144;
        int v = j & 3, ln = (j >> 2) & 63;
        int ntly = j >> 8;            // ly*12 + nt
        int nt = ntly % 12, ly = ntly / 12;
        int k = 8*(ln >> 4) + 2*v;
        int col = 16*nt + (ln & 15);
        const float* s = dlw2 + ly*6144;       // [32][192]
        bf2[j] = pack2(s[k*192 + col], s[(k+1)*192 + col]);
      }
    }
    return;
  }
  if (b < 7 + 2*NT){
    int bb = b - 7;
    int ent = bb & (NT - 1);
    int layer = bb >> 11;       // NT = 2048
    float bas[10];
    lut_basis(ent, bas);
    __shared__ float h[192];
    if (t < 192){
      int f = t >> 6, l = t & 63;       // f: 0=A, 1=B, 2=C
      const float* w1 = (f < 2) ? (fABw1 + (layer*2 + f) * 640)
                                : (fCw1 + layer * 640);
      float a = 0.f;
#pragma unroll
      for (int k = 0; k < 10; k++) a += bas[k] * w1[k*64 + l];
      h[t] = geluf(a);
    }
    __syncthreads();
    float a = 0.f;
    if (t < 192){
      int f = t / 96, j = t - 96 * f;
      const float* w2 = fABw2 + (layer*2 + f) * 6144;
      for (int l = 0; l < 64; l++) a += h[f*64 + l] * w2[l*96 + j];
    } else {
      int j = t - 192;
      const float* w2 = fCw2 + layer * 12288;
      for (int l = 0; l < 64; l++) a += h[128 + l] * w2[l*192 + j];
    }
    lutH[((long)(layer * NT + ent)) * 384 + t] = f16b(a);
    return;
  }
  // init LUT: 6 entries per block (384 = 6*64 threads)
  int blk = b - 7 - 2*NT;
  int ent = blk * 6 + (t >> 6);
  if (ent >= NT) return;
  int tl = t & 63;
  int p = tl >> 5, jj = tl & 31;
  float bas[10];
  lut_basis(ent, bas);
  const float* w1 = f01w1 + p * 640;
  const float* w2 = f01w2 + p * 2048;
  float W = 0.f;
  for (int l = 0; l < 64; l++){
    float a = 0.f;
#pragma unroll
    for (int k = 0; k < 10; k++) a += bas[k] * w1[k*64 + l];
    W += geluf(a) * w2[l*32 + jj];
  }
  lut01H[(long)ent * 64 + tl] = f16b(W);
}

// ---------------- merged: edge degree count + node init ---------------------
__global__ __launch_bounds__(256) void countnode_k(
    const int* __restrict__ esrc, const int* __restrict__ edst,
    int* __restrict__ cntd, int* __restrict__ cnts,
    const int* __restrict__ az, const float* __restrict__ embedF,
    const float* __restrict__ w1T /*[32][8]*/, const float* __restrict__ w2T /*[32][32]*/,
    float* __restrict__ xn)
{
  if (blockIdx.x < NE/256){
    int e = blockIdx.x * 256 + threadIdx.x;
    atomicAdd(cntd + edst[e], 1);
    atomicAdd(cnts + esrc[e], 1);
    return;
  }
  int n = (blockIdx.x - NE/256) * 256 + threadIdx.x;
  if (n >= NN) return;
  int z = az[n];
  float ee[8];
#pragma unroll
  for (int k = 0; k < 8; k++) ee[k] = embedF[z * 8 + k];
  float hid[32];
#pragma unroll
  for (int l = 0; l < 32; l++){
    float a = 0.f;
#pragma unroll
    for (int k = 0; k < 8; k++) a += ee[k] * w1T[l * 8 + k];
    hid[l] = geluf(a);
  }
  float* row = xn + (long)n * 96;
#pragma unroll
  for (int j = 0; j < 32; j++){
    float a = 0.f;
#pragma unroll
    for (int l = 0; l < 32; l++) a += hid[l] * w2T[j * 32 + l];
    row[j] = a;
  }
#pragma unroll
  for (int j = 32; j < 96; j++) row[j] = 0.f;
}

// ---------------- both prefix sums in one launch ----------------------------
__global__ __launch_bounds__(1024) void prefix_k(
    const int* __restrict__ cntd, int* __restrict__ doff, int* __restrict__ curd,
    const int* __restrict__ cnts, int* __restrict__ soff, int* __restrict__ curs)
{
  const int* cnt = blockIdx.x ? cnts : cntd;
  int* off = blockIdx.x ? soff : doff;
  int* cur = blockIdx.x ? curs : curd;
  __shared__ int part[1024];
  int t = threadIdx.x;
  int base = t * 20;
  int s = 0;
  for (int i = 0; i < 20; i++){ int idx = base + i; if (idx < NN) s += cnt[idx]; }
  part[t] = s; __syncthreads();
  for (int d = 1; d < 1024; d <<= 1){
    int v = (t >= d) ? part[t - d] : 0;
    __syncthreads();
    part[t] += v;
    __syncthreads();
  }
  int run = (t == 0) ? 0 : part[t - 1];
  for (int i = 0; i < 20; i++){
    int idx = base + i;
    if (idx < NN){ off[idx] = run; cur[idx] = run; run += cnt[idx]; }
  }
  if (t == 0) off[NN] = NE;
}

// p = dst-sorted slot of edge e; q = src-sorted slot; qpos[p]=q
__global__ void fill_comb(const int* __restrict__ esrc, const int* __restrict__ edst,
                          int* __restrict__ curd, int* __restrict__ curs,
                          int* __restrict__ srcS, int* __restrict__ dstS,
                          int* __restrict__ qpos){
  int e = blockIdx.x * 256 + threadIdx.x;
  if (e >= NE) return;
  int s = esrc[e], d = edst[e];
  int p = atomicAdd(curd + d, 1);
  srcS[p] = s; dstS[p] = d;
  int q = atomicAdd(curs + s, 1);
  qpos[p] = q;
}

// ---------------- edge init: p-row (dst side) + scattered q-row (src side) --
__global__ __launch_bounds__(256) void edge_init(
    const float* __restrict__ pos, const int* __restrict__ srcS,
    const int* __restrict__ dstS, const int* __restrict__ qpos,
    float* __restrict__ els,
    unsigned short* __restrict__ pbuf0, unsigned short* __restrict__ qbuf0,
    const float* __restrict__ w1T /*dl1w1T [32][4]*/, const float* __restrict__ w2T /*[32][32]*/,
    const unsigned int* __restrict__ lut01)
{
  int p = blockIdx.x * 256 + threadIdx.x;
  if (p >= NE) return;
  int s = srcS[p], d = dstS[p];
  float x = pos[s*3+0] - pos[d*3+0];
  float y = pos[s*3+1] - pos[d*3+1];
  float z = pos[s*3+2] - pos[d*3+2];
  float L = sqrtf(x*x + y*y + z*z + 1e-12f);
  float iv = 1.0f / fmaxf(L, 1e-6f);
  els[p] = L;

  float u = L - 2.0f;   // 2*(len/MAXR - 1), MAXR=2
  float cut = 0.5f * (1.0f - cosf(3.14159265358979323f * u));
  cut = (u > 0.0f) ? 0.0f : cut;
  cut = (u < -1.0f) ? 1.0f : cut;
  float xe0 = cut, cc = cut * 1.7320508075688772f * iv;
  float xe1 = cc*x, xe2 = cc*y, xe3 = cc*z;
  float hid[32];
#pragma unroll
  for (int l = 0; l < 32; l++){
    float a = xe0*w1T[l*4+0] + xe1*w1T[l*4+1] + xe2*w1T[l*4+2] + xe3*w1T[l*4+3];
    hid[l] = geluf(a);
  }
  float xeh[32];
#pragma unroll
  for (int j = 0; j < 32; j++){
    float a = 0.f;
#pragma unroll
    for (int l = 0; l < 32; l++) a += hid[l] * w2T[j*32 + l];
    xeh[j] = a;
  }
  float tt = fminf(L * ((float)(NT-1) / 1.7321f), (float)(NT-1) - 0.001f);
  int i0 = (int)tt; float tfv = tt - (float)i0;
  h2f tf2; tf2.x = (_Float16)tfv; tf2.y = tf2.x;
  h2f h05; h05.x = (_Float16)0.5f; h05.y = h05.x;
  const unsigned int* rA = lut01 + i0 * 32;
  const unsigned int* rB = rA + 32;

  unsigned int xp[16];
#pragma unroll
  for (int jp = 0; jp < 16; jp++)
    xp[jp] = pack2(xeh[2*jp] * 0.0625f, xeh[2*jp+1] * 0.0625f);

  unsigned int du[16], au[16];
#pragma unroll
  for (int q = 0; q < 4; q++){
    uint4 a = ((const uint4*)rA)[q];
    uint4 b = ((const uint4*)rB)[q];
    du[4*q+0] = h2u(u2h(lerp2(a.x, b.x, tf2)) * u2h(xp[4*q+0]));
    du[4*q+1] = h2u(u2h(lerp2(a.y, b.y, tf2)) * u2h(xp[4*q+1]));
    du[4*q+2] = h2u(u2h(lerp2(a.z, b.z, tf2)) * u2h(xp[4*q+2]));
    du[4*q+3] = h2u(u2h(lerp2(a.w, b.w, tf2)) * u2h(xp[4*q+3]));
  }
#pragma unroll
  for (int q = 0; q < 4; q++){
    uint4 a = ((const uint4*)(rA + 16))[q];
    uint4 b = ((const uint4*)(rB + 16))[q];
    au[4*q+0] = h2u(u2h(lerp2(a.x, b.x, tf2)) * u2h(xp[4*q+0]) * h05);
    au[4*q+1] = h2u(u2h(lerp2(a.y, b.y, tf2)) * u2h(xp[4*q+1]) * h05);
    au[4*q+2] = h2u(u2h(lerp2(a.z, b.z, tf2)) * u2h(xp[4*q+2]) * h05);
    au[4*q+3] = h2u(u2h(lerp2(a.w, b.w, tf2)) * u2h(xp[4*q+3]) * h05);
  }
  unsigned short* prow = pbuf0 + (long)p * 64;
  unsigned short* qrow = qbuf0 + (long)qpos[p] * 64;
#pragma unroll
  for (int q = 0; q < 4; q++){
    ((uint4*)prow)[q]      = ((uint4*)du)[q];
    ((uint4*)(prow+32))[q] = ((uint4*)au)[q];
  }
  unsigned int nd[16];
#pragma unroll
  for (int i = 0; i < 16; i++) nd[i] = du[i] ^ 0x80008000u;  // negate packed f16
#pragma unroll
  for (int q = 0; q < 4; q++){
    ((uint4*)qrow)[q]      = ((uint4*)nd)[q];
    ((uint4*)(qrow+32))[q] = ((uint4*)au)[q];
  }
}

// 16 nodes per 256-thread block, 16 threads/node, uint2-vectorized streams
__global__ __launch_bounds__(256) void gather_init(
    const int* __restrict__ doff, const int* __restrict__ soff,
    const unsigned short* __restrict__ pbuf0, const unsigned short* __restrict__ qbuf0,
    float* __restrict__ xn, unsigned int* __restrict__ xnh)
{
  int g = threadIdx.x >> 4;          // 0..15
  int c4 = threadIdx.x & 15;         // 4-half group within 64-half row
  int n = blockIdx.x * 16 + g;
  if (n >= NN) return;
  const uint2* p2 = (const uint2*)pbuf0;   // row = 16 uint2
  const uint2* q2 = (const uint2*)qbuf0;
  float a0 = 0.f, a1 = 0.f, a2 = 0.f, a3 = 0.f;
  int d1 = doff[n+1];
  for (int p = doff[n]; p < d1; p++){
    uint2 v = p2[(long)p * 16 + c4];
    h2f lo = u2h(v.x), hi = u2h(v.y);
    a0 += (float)lo.x; a1 += (float)lo.y; a2 += (float)hi.x; a3 += (float)hi.y;
  }
  int s1 = soff[n+1];
  for (int q = soff[n]; q < s1; q++){
    uint2 v = q2[(long)q * 16 + c4];
    h2f lo = u2h(v.x), hi = u2h(v.y);
    a0 += (float)lo.x; a1 += (float)lo.y; a2 += (float)hi.x; a3 += (float)hi.y;
  }
  float4 v4; v4.x = 16.f*a0; v4.y = 16.f*a1; v4.z = 16.f*a2; v4.w = 16.f*a3;
  *(float4*)(xn + (long)n * 96 + 32 + 4*c4) = v4;   // cols 32..95
  uint2 w; w.x = pack2(v4.x, v4.y); w.y = pack2(v4.z, v4.w);
  *(uint2*)(xnh + n * 48 + 16 + 2*c4) = w;
  if (c4 < 8){
    float4 t = *(const float4*)(xn + (long)n * 96 + 4*c4);
    uint2 w0; w0.x = pack2(t.x, t.y); w0.y = pack2(t.z, t.w);
    *(uint2*)(xnh + n * 48 + 2*c4) = w0;
  }
}

// ---------------- conv layer via MFMA: 1 wave/block, batched loads ----------
// pass-1 issues all 24 independent uint4 loads per ktp window back-to-back
// into register arrays (MLP ~24) before compute.
// Per wave: 64 edges. pass1 hd[64][32] = G[64][192] @ dw1; pass2 d = hdg @ dw2.
// A-frag: lane -> row (lane&15)+16mt, k = 8*(lane>>4)+j
// B-frag: lane -> col (lane&15)+16nt, k = 8*(lane>>4)+j (pre-packed bf1/bf2)
// C/D:    lane -> col (lane&15), row = 4*(lane>>4)+reg
// p-row -> pbuf[p]; q-row -> qbuf[qpos[p]] (scatter; gather streams both sides)
__global__ __launch_bounds__(64) void layer_k(
    const int* __restrict__ srcS, const int* __restrict__ dstS,
    const int* __restrict__ qpos,
    const float* __restrict__ els, const unsigned int* __restrict__ xnh,
    unsigned short* __restrict__ pbuf, unsigned short* __restrict__ qbuf,
    const unsigned int* __restrict__ lut,
    const unsigned int* __restrict__ bf1, const unsigned int* __restrict__ bf2)
{
  __shared__ unsigned int wb[1092];   // [64][17]-uint image, one wave
  int lane = threadIdx.x;
  int g = lane >> 4, r15 = lane & 15;
  int wbase = blockIdx.x * 64;

  // per-mt metadata (fragment-side edges: re = wbase + 16mt + r15)
  const unsigned int* xsP[4]; const unsigned int* xdP[4];
  const unsigned int* rAm[4]; const unsigned int* rBm[4];
  h2f tfm[4];
#pragma unroll
  for (int mt = 0; mt < 4; mt++){
    int re = wbase + 16*mt + r15;
    xsP[mt] = xnh + srcS[re] * 48;
    xdP[mt] = xnh + dstS[re] * 48;
    float L = els[re];
    float tt = fminf(L * ((float)(NT-1) / 1.7321f), (float)(NT-1) - 0.001f);
    int i0 = (int)tt; float tfv = tt - (float)i0;
    h2f tf; tf.x = (_Float16)tfv; tf.y = tf.x;
    tfm[mt] = tf;
    rAm[mt] = lut + (long)i0 * 192;
    rBm[mt] = rAm[mt] + 192;
  }
  // own-edge metadata (output row p = wbase + lane)
  int p = wbase + lane;
  int qq = qpos[p];
  const unsigned int *rAo, *rBo; h2f tfo;
  {
    float L = els[p];
    float tt = fminf(L * ((float)(NT-1) / 1.7321f), (float)(NT-1) - 0.001f);
    int i0 = (int)tt; float tfv = tt - (float)i0;
    tfo.x = (_Float16)tfv; tfo.y = tfo.x;
    rAo = lut + (long)i0 * 192;
    rBo = rAo + 192;
  }
  h2f c32; c32.x = (_Float16)0.03125f;  c32.y = c32.x;
  h2f c64; c64.x = (_Float16)0.015625f; c64.y = c64.x;
  h2f h05; h05.x = (_Float16)0.5f;      h05.y = h05.x;
  f32x4 zf = {0.f, 0.f, 0.f, 0.f};

  // ---- pass 1 (batched loads per ktp window) ----
  f32x4 acc[4][2];
#pragma unroll
  for (int mt = 0; mt < 4; mt++){ acc[mt][0] = zf; acc[mt][1] = zf; }

#pragma unroll
  for (int ktp = 0; ktp < 3; ktp++){      // x-uint window 16*ktp..+16
    int off = 16*ktp + 4*g;
    uint4 bg0 = *(const uint4*)(bf1 + (((ktp  )*2 + 0)*64 + lane)*4);
    uint4 bg1 = *(const uint4*)(bf1 + (((ktp  )*2 + 1)*64 + lane)*4);
    uint4 ba0 = *(const uint4*)(bf1 + (((ktp+3)*2 + 0)*64 + lane)*4);
    uint4 ba1 = *(const uint4*)(bf1 + (((ktp+3)*2 + 1)*64 + lane)*4);
    uint4 xs4[4], xd4[4], waA[4], waB[4], wbA[4], wbB[4];
#pragma unroll
    for (int mt = 0; mt < 4; mt++){
      xs4[mt] = *(const uint4*)(xsP[mt] + off);
      xd4[mt] = *(const uint4*)(xdP[mt] + off);
      waA[mt] = *(const uint4*)(rAm[mt] + off);
      waB[mt] = *(const uint4*)(rBm[mt] + off);
      wbA[mt] = *(const uint4*)(rAm[mt] + 48 + off);
      wbB[mt] = *(const uint4*)(rBm[mt] + 48 + off);
    }
#pragma unroll
    for (int mt = 0; mt < 4; mt++){
      h2f tf = tfm[mt];
      uint4 fg, fa;
      fg.x = h2u(u2h(lerp2(waA[mt].x, waB[mt].x, tf)) * ((u2h(xd4[mt].x) - u2h(xs4[mt].x)) * c32));
      fg.y = h2u(u2h(lerp2(waA[mt].y, waB[mt].y, tf)) * ((u2h(xd4[mt].y) - u2h(xs4[mt].y)) * c32));
      fg.z = h2u(u2h(lerp2(waA[mt].z, waB[mt].z, tf)) * ((u2h(xd4[mt].z) - u2h(xs4[mt].z)) * c32));
      fg.w = h2u(u2h(lerp2(waA[mt].w, waB[mt].w, tf)) * ((u2h(xd4[mt].w) - u2h(xs4[mt].w)) * c32));
      fa.x = h2u(u2h(lerp2(wbA[mt].x, wbB[mt].x, tf)) * ((u2h(xd4[mt].x) + u2h(xs4[mt].x)) * c64));
      fa.y = h2u(u2h(lerp2(wbA[mt].y, wbB[mt].y, tf)) * ((u2h(xd4[mt].y) + u2h(xs4[mt].y)) * c64));
      fa.z = h2u(u2h(lerp2(wbA[mt].z, wbB[mt].z, tf)) * ((u2h(xd4[mt].z) + u2h(xs4[mt].z)) * c64));
      fa.w = h2u(u2h(lerp2(wbA[mt].w, wbB[mt].w, tf)) * ((u2h(xd4[mt].w) + u2h(xs4[mt].w)) * c64));
      acc[mt][0] = __builtin_amdgcn_mfma_f32_16x16x32_f16(u4h8(fg), u4h8(bg0), acc[mt][0], 0, 0, 0);
      acc[mt][1] = __builtin_amdgcn_mfma_f32_16x16x32_f16(u4h8(fg), u4h8(bg1), acc[mt][1], 0, 0, 0);
      acc[mt][0] = __builtin_amdgcn_mfma_f32_16x16x32_f16(u4h8(fa), u4h8(ba0), acc[mt][0], 0, 0, 0);
      acc[mt][1] = __builtin_amdgcn_mfma_f32_16x16x32_f16(u4h8(fa), u4h8(ba1), acc[mt][1], 0, 0, 0);
    }
  }

  // ---- gelu + transpose hdg (D layout -> row-major LDS -> A-frags) ----
#pragma unroll
  for (int mt = 0; mt < 4; mt++)
#pragma unroll
    for (int nt = 0; nt < 2; nt++)
#pragma unroll
      for (int i = 0; i < 4; i++){
        float v = geluf(32.f * acc[mt][nt][i]) * 0.015625f;
        float o = __shfl_xor(v, 1);
        if (!(lane & 1))
          wb[(16*mt + 4*g + i)*17 + 8*nt + (r15 >> 1)] = pack2(v, o);
      }
  wsync();
  uint4 af[4];
#pragma unroll
  for (int mt = 0; mt < 4; mt++){
    int row = 16*mt + r15;
    af[mt].x = wb[row*17 + 4*g + 0];
    af[mt].y = wb[row*17 + 4*g + 1];
    af[mt].z = wb[row*17 + 4*g + 2];
    af[mt].w = wb[row*17 + 4*g + 3];
  }
  wsync();

  // ---- pass 2: per 16-col block np (cols 16np.. and 96+16np..) ----
  unsigned int* prow = (unsigned int*)(pbuf + (long)p * 96);
  unsigned int* qrow = (unsigned int*)(qbuf + (long)qq * 96);
  for (int np = 0; np < 6; np++){
    uint4 b1 = *(const uint4*)(bf2 + ((np    )*64 + lane)*4);
    uint4 b2 = *(const uint4*)(bf2 + ((np + 6)*64 + lane)*4);
    // own-edge Wc loads issued early (overlap with MFMA below)
    uint4 ca0 = *(const uint4*)(rAo + 96  + 8*np);
    uint4 ca1 = *(const uint4*)(rAo + 100 + 8*np);
    uint4 cb0 = *(const uint4*)(rBo + 96  + 8*np);
    uint4 cb1 = *(const uint4*)(rBo + 100 + 8*np);
    uint4 ka0 = *(const uint4*)(rAo + 144 + 8*np);
    uint4 ka1 = *(const uint4*)(rAo + 148 + 8*np);
    uint4 kb0 = *(const uint4*)(rBo + 144 + 8*np);
    uint4 kb1 = *(const uint4*)(rBo + 148 + 8*np);
    f32x4 d1a[4], d2a[4];
#pragma unroll
    for (int mt = 0; mt < 4; mt++){
      d1a[mt] = __builtin_amdgcn_mfma_f32_16x16x32_f16(u4h8(af[mt]), u4h8(b1), zf, 0, 0, 0);
      d2a[mt] = __builtin_amdgcn_mfma_f32_16x16x32_f16(u4h8(af[mt]), u4h8(b2), zf, 0, 0, 0);
    }
#pragma unroll
    for (int mt = 0; mt < 4; mt++)
#pragma unroll
      for (int i = 0; i < 4; i++){
        float v1 = d1a[mt][i], v2 = d2a[mt][i];
        float o1 = __shfl_xor(v1, 1);
        float o2 = __shfl_xor(v2, 1);
        if (!(lane & 1)){
          int r = 16*mt + 4*g + i;
          wb[r*17 + (r15 >> 1)]     = pack2(v1, o1);
          wb[r*17 + 8 + (r15 >> 1)] = pack2(v2, o2);
        }
      }
    wsync();
    unsigned int d1u[8], d2u[8];
#pragma unroll
    for (int u = 0; u < 8; u++){
      d1u[u] = wb[lane*17 + u];
      d2u[u] = wb[lane*17 + 8 + u];
    }
    wsync();
    unsigned int c1u[8] = {lerp2(ca0.x,cb0.x,tfo), lerp2(ca0.y,cb0.y,tfo),
                           lerp2(ca0.z,cb0.z,tfo), lerp2(ca0.w,cb0.w,tfo),
                           lerp2(ca1.x,cb1.x,tfo), lerp2(ca1.y,cb1.y,tfo),
                           lerp2(ca1.z,cb1.z,tfo), lerp2(ca1.w,cb1.w,tfo)};
    unsigned int c2u[8] = {lerp2(ka0.x,kb0.x,tfo), lerp2(ka0.y,kb0.y,tfo),
                           lerp2(ka0.z,kb0.z,tfo), lerp2(ka0.w,kb0.w,tfo),
                           lerp2(ka1.x,kb1.x,tfo), lerp2(ka1.y,kb1.y,tfo),
                           lerp2(ka1.z,kb1.z,tfo), lerp2(ka1.w,kb1.w,tfo)};
    unsigned int pv[8], qv[8];
#pragma unroll
    for (int u = 0; u < 8; u++){
      h2f t1 = u2h(c1u[u]) * u2h(d1u[u]);            // dv (true/64)
      h2f t2 = (u2h(c2u[u]) * u2h(d2u[u])) * h05;    // av (true/64)
      pv[u] = h2u(t1 + t2);
      qv[u] = h2u(t2 - t1);
    }
    *(uint4*)(prow + 8*np)     = *(uint4*)(pv);
    *(uint4*)(prow + 8*np + 4) = *(uint4*)(pv + 4);
    *(uint4*)(qrow + 8*np)     = *(uint4*)(qv);
    *(uint4*)(qrow + 8*np + 4) = *(uint4*)(qv + 4);
  }
}

// fused gather + node update + xnh repack; uint2-vectorized, 10 nodes/block
__global__ __launch_bounds__(256) void gather_upd(
    const int* __restrict__ doff, const int* __restrict__ soff,
    const unsigned short* __restrict__ pbuf, const unsigned short* __restrict__ qbuf,
    float* __restrict__ xn, unsigned int* __restrict__ xnh)
{
  int g = threadIdx.x / 24;
  int c4 = threadIdx.x - 24 * g;     // 4-half group within 96-half row
  if (g >= 10) return;
  int n = blockIdx.x * 10 + g;
  if (n >= NN) return;
  const uint2* p2 = (const uint2*)pbuf;   // row = 24 uint2
  const uint2* q2 = (const uint2*)qbuf;
  float a0 = 0.f, a1 = 0.f, a2 = 0.f, a3 = 0.f;
  int d1 = doff[n+1];
  for (int p = doff[n]; p < d1; p++){
    uint2 v = p2[(long)p * 24 + c4];
    h2f lo = u2h(v.x), hi = u2h(v.y);
    a0 += (float)lo.x; a1 += (float)lo.y; a2 += (float)hi.x; a3 += (float)hi.y;
  }
  int s1 = soff[n+1];
  for (int q = soff[n]; q < s1; q++){
    uint2 v = q2[(long)q * 24 + c4];
    h2f lo = u2h(v.x), hi = u2h(v.y);
    a0 += (float)lo.x; a1 += (float)lo.y; a2 += (float)hi.x; a3 += (float)hi.y;
  }
  float4 xo = *(float4*)(xn + (long)n * 96 + 4*c4);
  xo.x -= 6.4f * a0; xo.y -= 6.4f * a1; xo.z -= 6.4f * a2; xo.w -= 6.4f * a3;
  *(float4*)(xn + (long)n * 96 + 4*c4) = xo;
  uint2 w; w.x = pack2(xo.x, xo.y); w.y = pack2(xo.z, xo.w);
  *(uint2*)(xnh + n * 48 + 2*c4) = w;
}

// ---------------- column sum over nodes -------------------------------------
__global__ void colsum(const float* __restrict__ xn, float* __restrict__ nodesum){
  int col = threadIdx.x % 96;
  int seg = threadIdx.x / 96;
  int stripe = blockIdx.x * 2 + seg;   // 0..399
  float acc = 0.f;
  for (int n = stripe; n < NN; n += 400) acc += xn[(long)n * 96 + col];
  unsafeAtomicAdd(nodesum + col, acc);
}

// ---------------- project to 16 outputs, scale, fp32 store ------------------
__global__ void project(const float* __restrict__ nodesum, const float* __restrict__ siT,
                        float* __restrict__ out){
  int j = threadIdx.x;
  if (j < 16){
    float a = 0.f;
#pragma unroll
    for (int c = 0; c < 96; c++) a += nodesum[c] * siT[j*96 + c];
    out[j] = a * 0.007071067811865475f;   // 1/sqrt(20000)
  }
}

// ---------------- host side -------------------------------------------------
extern "C" void kernel_launch(void* const* d_in, const int* in_sizes, int n_in,
                              void* d_out, int out_size, void* d_ws, size_t ws_size,
                              hipStream_t stream){
  const float* pos  = (const float*)d_in[0];
  const int* atom_z = (const int*)d_in[1];
  const int* esrc   = (const int*)d_in[2];
  const int* edst   = (const int*)d_in[3];

  float* ws      = (float*)d_ws;
  float* xn      = ws;                  // 1,920,000
  float* nodesum = ws + 1920000;        // 96
  float* WB      = ws + 1920096;        // 4,128 fp32 weights
  unsigned int* bf1   = (unsigned int*)(ws + 1924224);  // 6,144
  unsigned int* bf2   = (unsigned int*)(ws + 1930368);  // 6,144
  unsigned int* lutL  = (unsigned int*)(ws + 1936512);  // 786,432 (3 MB)
  unsigned int* lut01 = (unsigned int*)(ws + 2722944);  // 65,536
  unsigned int* xnh   = (unsigned int*)(ws + 2788480);  // 960,000 (f16 rows)
  float* els    = ws + 3748480;                 // 320,000 edge lengths
  int*   cntd   = (int*)(ws + 4068480);         // 20,000
  int*   cnts   = cntd + 20000;                 // 20,000 (contiguous for 1 memset)
  int*   curd   = cnts + 20000;                 // 20,000
  int*   curs   = curd + 20000;                 // 20,000
  int*   doff   = curs + 20000;                 // 20,004
  int*   soff   = doff + 20004;                 // 20,004  -> ends 4,188,488
  int*   srcS   = soff + 20004;                 // 320,000 -> ends 4,508,488
  int*   dstS   = srcS + 320000;                // 320,000 -> ends 4,828,488
  int*   qpos   = dstS + 320000;                // 320,000 -> ends 5,148,488
  // buffers at verified round-10..16 offsets (>= 5,468,496 > int arrays):
  //   pbufL: [ 5,468,496 .. 20,828,496)   qbufL: [20,828,496 .. 36,188,496)
  //   pbuf0: [ 5,468,496 .. 15,708,496)   qbuf0: [15,708,496 .. 25,948,496)
  // (init aliases layer space CROSS-PHASE only; init-phase disjoint.)
  // end = 36,188,496 floats = 144.8 MB
  unsigned short* pbufL = (unsigned short*)(ws + 5468496);
  unsigned short* qbufL = (unsigned short*)(ws + 20828496);
  unsigned short* pbuf0 = (unsigned short*)(ws + 5468496);
  unsigned short* qbuf0 = (unsigned short*)(ws + 15708496);

  float* embedF = WB + 0;        // 160
  float* dl0w1T = WB + 160;      // 256   [32][8]
  float* dl0w2T = WB + 416;      // 1024  [32][32]
  float* dl1w1T = WB + 1440;     // 128   [32][4]
  float* dl1w2T = WB + 1568;     // 1024  [32][32]
  float* siT    = WB + 2592;     // 1536  [16][96]

  hipMemsetAsync(cntd, 0, 40000 * 4, stream);
  hipMemsetAsync(nodesum, 0, 96 * 4, stream);

  TTab tb;
  int ti = 0;
  auto add = [&](const void* s, float* dst, int R, int C, int tr){
    tb.e[ti].src = (const float*)s; tb.e[ti].dst = dst;
    tb.e[ti].R = R; tb.e[ti].C = C; tb.e[ti].trans = tr; ti++;
  };
  add(d_in[4],  embedF, 20, 8, 0);
  add(d_in[5],  dl0w1T, 8, 32, 1);
  add(d_in[6],  dl0w2T, 32, 32, 1);
  add(d_in[7],  dl1w1T, 4, 32, 1);
  add(d_in[8],  dl1w2T, 32, 32, 1);
  add(d_in[17], siT, 96, 16, 1);

  // weight prep (convw + MFMA B-fragment pack + both LUTs) in one launch
  prep_k<<<7 + 2*NT + (NT + 5)/6, 384, 0, stream>>>(
      tb, (const float*)d_in[11], (const float*)d_in[12],
      (const float*)d_in[13], (const float*)d_in[14], (unsigned short*)lutL,
      (const float*)d_in[9], (const float*)d_in[10], (unsigned short*)lut01,
      (const float*)d_in[15], (const float*)d_in[16], bf1, bf2);
  countnode_k<<<NE/256 + (NN + 255)/256, 256, 0, stream>>>(
      esrc, edst, cntd, cnts, atom_z, embedF, dl0w1T, dl0w2T, xn);
  prefix_k<<<2, 1024, 0, stream>>>(cntd, doff, curd, cnts, soff, curs);
  fill_comb<<<(NE + 255)/256, 256, 0, stream>>>(esrc, edst, curd, curs,
                                                srcS, dstS, qpos);
  edge_init<<<(NE + 255)/256, 256, 0, stream>>>(
      pos, srcS, dstS, qpos, els, pbuf0, qbuf0, dl1w1T, dl1w2T, lut01);
  gather_init<<<(NN + 15)/16, 256, 0, stream>>>(doff, soff, pbuf0, qbuf0, xn, xnh);

  for (int i = 0; i < 2; i++){
    layer_k<<<NE/64, 64, 0, stream>>>(
        srcS, dstS, qpos, els, xnh, pbufL, qbufL,
        lutL + (long)i * NT * 192, bf1 + i*3072, bf2 + i*3072);
    gather_upd<<<(NN + 9)/10, 256, 0, stream>>>(doff, soff, pbufL, qbufL,
                                                xn, xnh);
  }
  colsum<<<200, 192, 0, stream>>>(xn, nodesum);
  project<<<1, 64, 0, stream>>>(nodesum, siT, (float*)d_out);
}